// Round 4
// baseline (271.855 us; speedup 1.0000x reference)
//
#include <hip/hip_runtime.h>
#include <math.h>

#define BB 4
#define NN 512
#define DD 64
#define EPS 1e-5f
#define NEG_SLOPE 0.01f
#define TI 8   // i-rows per block in attn_kernel
#define JC 8   // j-chunks; j's per block = NN/JC = 64

typedef float f32x4 __attribute__((ext_vector_type(4)));

// Kernel A: per-row LayerNorm folded into the two projections.
// One wave (64 lanes) per row; lane d holds i_em[row, d].
__global__ void __launch_bounds__(256)
stats_kernel(const float* __restrict__ i_em,
             const float* __restrict__ W_a,
             const float* __restrict__ gamma,
             const float* __restrict__ beta,
             float* __restrict__ sq,
             float* __restrict__ sk) {
    int row  = (blockIdx.x * blockDim.x + threadIdx.x) >> 6;   // global wave id
    int lane = threadIdx.x & 63;
    if (row >= BB * NN) return;

    float x = i_em[row * DD + lane];

    float s = x;
    #pragma unroll
    for (int off = 32; off >= 1; off >>= 1) s += __shfl_xor(s, off, 64);
    float mu = s * (1.0f / DD);

    float dx = x - mu;
    float v = dx * dx;
    #pragma unroll
    for (int off = 32; off >= 1; off >>= 1) v += __shfl_xor(v, off, 64);
    float rstd = rsqrtf(v * (1.0f / DD) + EPS);

    float xn = dx * rstd * gamma[lane] + beta[lane];
    float pq = xn * W_a[lane];
    float pk = xn * W_a[DD + lane];
    #pragma unroll
    for (int off = 32; off >= 1; off >>= 1) {
        pq += __shfl_xor(pq, off, 64);
        pk += __shfl_xor(pk, off, 64);
    }
    if (lane == 0) { sq[row] = pq; sk[row] = pk; }
}

// Kernel B: 1D grid of 2048 blocks, XCD-swizzled so XCD x owns a contiguous
// 256-row (32 MB) band of value. Block id decomposes to (ib, jc):
// rows ib*8..ib*8+7, j chunk [jc*64, jc*64+64).
// __launch_bounds__(256, 4): 128-VGPR cap — the (256,8)=64-VGPR clamp of the
// previous round risked scratch spill (xi[8]=32 VGPR + hoisted xj + softmax
// regs), i.e. hidden HBM traffic inside a store-bound kernel.
__global__ void __launch_bounds__(256, 4)
attn_kernel(const float* __restrict__ i_em,
            const float* __restrict__ sq,
            const float* __restrict__ sk,
            const float* __restrict__ b_a,
            float* __restrict__ alphas,
            float* __restrict__ value) {
    // ---- XCD-aware swizzle: block n dispatches to XCD n%8 (round-robin);
    // remap so same-XCD blocks cover contiguous ids -> contiguous addresses.
    const int nwg = (BB * NN / TI) * JC;      // 2048, divisible by 8
    const int per = nwg >> 3;                 // 256 blocks per XCD
    const int orig = blockIdx.x;
    const int id   = (orig & 7) * per + (orig >> 3);

    const int ib   = id >> 3;          // 0 .. 255
    const int jc   = id & 7;           // 0 .. 7
    const int i0g  = ib * TI;          // global row base (b*NN + i0)
    const int b    = i0g >> 9;         // / NN
    const int t    = threadIdx.x;
    const int lane = t & 63;
    const int w    = t >> 6;           // wave id 0..3

    // ---- phase 1 (jc==0 blocks only): softmax over j, 2 rows per wave ----
    if (jc == 0) {
        const float bias = b_a[0];
        const float* skb = sk + b * NN;

        float sv[8];
        #pragma unroll
        for (int k = 0; k < 8; ++k) sv[k] = skb[lane + k * 64];

        #pragma unroll
        for (int rr = 0; rr < 2; ++rr) {
            const int row  = i0g + w + rr * 4;     // global row (b*NN + i)
            const float si = sq[row] + bias;

            float e[8];
            float m = -INFINITY;
            #pragma unroll
            for (int k = 0; k < 8; ++k) {
                float s = si + sv[k];
                s = (s >= 0.f) ? s : NEG_SLOPE * s;
                e[k] = s;
                m = fmaxf(m, s);
            }
            #pragma unroll
            for (int off = 32; off >= 1; off >>= 1) m = fmaxf(m, __shfl_xor(m, off, 64));

            float sum = 0.f;
            #pragma unroll
            for (int k = 0; k < 8; ++k) { e[k] = expf(e[k] - m); sum += e[k]; }
            #pragma unroll
            for (int off = 32; off >= 1; off >>= 1) sum += __shfl_xor(sum, off, 64);
            const float inv = 1.0f / sum;

            float* arow = alphas + (size_t)row * NN;
            #pragma unroll
            for (int k = 0; k < 8; ++k)
                arow[lane + k * 64] = e[k] * inv;
        }
    }

    // ---- phase 2: outer-product value writes for j-chunk ----
    const f32x4* em4 = (const f32x4*)i_em;
    const int d4 = t & 15;             // which float4 of D=64
    const int jg = t >> 4;             // j group 0..15
    const int j0 = jc * (NN / JC);     // chunk base
    const f32x4* emb = em4 + (size_t)b * NN * 16;

    f32x4 xi[TI];
    #pragma unroll
    for (int r = 0; r < TI; ++r) xi[r] = em4[(size_t)(i0g + r) * 16 + d4];

    f32x4* out0 = (f32x4*)value + (size_t)i0g * (NN * 16) + d4;

    #pragma unroll
    for (int k = 0; k < NN / JC / 16; ++k) {   // 4 iterations, fully unrolled
        const int j = j0 + jg + k * 16;
        const f32x4 xj = emb[j * 16 + d4];     // L2-hit; 1 load feeds TI stores
        #pragma unroll
        for (int r = 0; r < TI; ++r) {
            f32x4 o = xi[r] * xj;
            out0[(size_t)r * (NN * 16) + j * 16] = o;
        }
    }
}

extern "C" void kernel_launch(void* const* d_in, const int* in_sizes, int n_in,
                              void* d_out, int out_size, void* d_ws, size_t ws_size,
                              hipStream_t stream) {
    const float* i_em  = (const float*)d_in[0];
    const float* W_a   = (const float*)d_in[1];
    const float* b_a   = (const float*)d_in[2];
    const float* gamma = (const float*)d_in[3];
    const float* beta  = (const float*)d_in[4];

    float* alphas = (float*)d_out;                        // B*N*N
    float* value  = (float*)d_out + (size_t)BB * NN * NN; // B*N*N*D

    float* sq = (float*)d_ws;          // B*N
    float* sk = sq + BB * NN;          // B*N

    // 2048 rows, 4 waves per 256-thread block -> 512 blocks
    stats_kernel<<<(BB * NN) / 4, 256, 0, stream>>>(i_em, W_a, gamma, beta, sq, sk);
    // 1D grid, XCD-swizzled inside the kernel
    attn_kernel<<<(BB * NN / TI) * JC, 256, 0, stream>>>(i_em, sq, sk, b_a, alphas, value);
}

// Round 5
// 270.794 us; speedup vs baseline: 1.0039x; 1.0039x over previous
//
#include <hip/hip_runtime.h>
#include <math.h>

#define BB 4
#define NN 512
#define DD 64
#define EPS 1e-5f
#define NEG_SLOPE 0.01f
#define TI 8   // i-rows per block in attn_kernel
#define JC 8   // j-chunks; j's per block = NN/JC = 64 (4 per wave-slot)

typedef float f32x4 __attribute__((ext_vector_type(4)));

// Kernel A: per-row LayerNorm folded into the two projections.
// One wave (64 lanes) per row; lane d holds i_em[row, d].
__global__ void __launch_bounds__(256)
stats_kernel(const float* __restrict__ i_em,
             const float* __restrict__ W_a,
             const float* __restrict__ gamma,
             const float* __restrict__ beta,
             float* __restrict__ sq,
             float* __restrict__ sk) {
    int row  = (blockIdx.x * blockDim.x + threadIdx.x) >> 6;   // global wave id
    int lane = threadIdx.x & 63;
    if (row >= BB * NN) return;

    float x = i_em[row * DD + lane];

    float s = x;
    #pragma unroll
    for (int off = 32; off >= 1; off >>= 1) s += __shfl_xor(s, off, 64);
    float mu = s * (1.0f / DD);

    float dx = x - mu;
    float v = dx * dx;
    #pragma unroll
    for (int off = 32; off >= 1; off >>= 1) v += __shfl_xor(v, off, 64);
    float rstd = rsqrtf(v * (1.0f / DD) + EPS);

    float xn = dx * rstd * gamma[lane] + beta[lane];
    float pq = xn * W_a[lane];
    float pk = xn * W_a[DD + lane];
    #pragma unroll
    for (int off = 32; off >= 1; off >>= 1) {
        pq += __shfl_xor(pq, off, 64);
        pk += __shfl_xor(pk, off, 64);
    }
    if (lane == 0) { sq[row] = pq; sk[row] = pk; }
}

// Kernel B: 2048 blocks (XCD-swizzled), block = (ib, jc): rows ib*8..+7,
// j-chunk [jc*64, jc*64+64).
// KEY CHANGE vs r4: phase 2 is split into an explicit LOAD PHASE (all 12
// global loads: xi[8] + xj[4]) followed by a PURE STORE PHASE (32 stores,
// no vmem loads). vmcnt counts loads AND stores in one in-order queue, so
// any load interleaved into the store burst forces a store-queue drain at
// its s_waitcnt — the one mechanism invariant across every variant so far.
__global__ void __launch_bounds__(256, 4)
attn_kernel(const float* __restrict__ i_em,
            const float* __restrict__ sq,
            const float* __restrict__ sk,
            const float* __restrict__ b_a,
            float* __restrict__ alphas,
            float* __restrict__ value) {
    // XCD-aware swizzle (nwg=2048, divisible by 8 -> bijective)
    const int nwg  = (BB * NN / TI) * JC;     // 2048
    const int per  = nwg >> 3;                // 256 per XCD
    const int orig = blockIdx.x;
    const int id   = (orig & 7) * per + (orig >> 3);

    const int ib   = id >> 3;          // 0 .. 255
    const int jc   = id & 7;           // 0 .. 7
    const int i0g  = ib * TI;          // global row base (b*NN + i0)
    const int b    = i0g >> 9;         // / NN
    const int t    = threadIdx.x;
    const int lane = t & 63;
    const int w    = t >> 6;           // wave id 0..3

    // ---- phase 1 (jc==0 blocks only): softmax over j, 2 rows per wave ----
    if (jc == 0) {
        const float bias = b_a[0];
        const float* skb = sk + b * NN;

        float sv[8];
        #pragma unroll
        for (int k = 0; k < 8; ++k) sv[k] = skb[lane + k * 64];

        #pragma unroll
        for (int rr = 0; rr < 2; ++rr) {
            const int row  = i0g + w + rr * 4;     // global row (b*NN + i)
            const float si = sq[row] + bias;

            float e[8];
            float m = -INFINITY;
            #pragma unroll
            for (int k = 0; k < 8; ++k) {
                float s = si + sv[k];
                s = (s >= 0.f) ? s : NEG_SLOPE * s;
                e[k] = s;
                m = fmaxf(m, s);
            }
            #pragma unroll
            for (int off = 32; off >= 1; off >>= 1) m = fmaxf(m, __shfl_xor(m, off, 64));

            float sum = 0.f;
            #pragma unroll
            for (int k = 0; k < 8; ++k) { e[k] = expf(e[k] - m); sum += e[k]; }
            #pragma unroll
            for (int off = 32; off >= 1; off >>= 1) sum += __shfl_xor(sum, off, 64);
            const float inv = 1.0f / sum;

            float* arow = alphas + (size_t)row * NN;
            #pragma unroll
            for (int k = 0; k < 8; ++k)
                arow[lane + k * 64] = e[k] * inv;
        }
    }

    // ---- phase 2a: LOAD PHASE — all 12 loads, no stores yet ----
    const f32x4* em4 = (const f32x4*)i_em;
    const int d4 = t & 15;             // which float4 of D=64
    const int jg = t >> 4;             // j group 0..15
    const int j0 = jc * (NN / JC);     // chunk base
    const f32x4* emb = em4 + (size_t)b * NN * 16;

    f32x4 xi[TI];
    #pragma unroll
    for (int r = 0; r < TI; ++r) xi[r] = em4[(size_t)(i0g + r) * 16 + d4];

    f32x4 xj[4];
    #pragma unroll
    for (int k = 0; k < 4; ++k) xj[k] = emb[(j0 + jg + k * 16) * 16 + d4];

    // ---- phase 2b: PURE STORE PHASE — 32 stores, zero load dependencies ----
    f32x4* out0 = (f32x4*)value + (size_t)i0g * (NN * 16) + d4;

    #pragma unroll
    for (int k = 0; k < 4; ++k) {
        const int j = j0 + jg + k * 16;
        #pragma unroll
        for (int r = 0; r < TI; ++r) {
            f32x4 o = xi[r] * xj[k];
            out0[(size_t)r * (NN * 16) + j * 16] = o;
        }
    }
}

extern "C" void kernel_launch(void* const* d_in, const int* in_sizes, int n_in,
                              void* d_out, int out_size, void* d_ws, size_t ws_size,
                              hipStream_t stream) {
    const float* i_em  = (const float*)d_in[0];
    const float* W_a   = (const float*)d_in[1];
    const float* b_a   = (const float*)d_in[2];
    const float* gamma = (const float*)d_in[3];
    const float* beta  = (const float*)d_in[4];

    float* alphas = (float*)d_out;                        // B*N*N
    float* value  = (float*)d_out + (size_t)BB * NN * NN; // B*N*N*D

    float* sq = (float*)d_ws;          // B*N
    float* sk = sq + BB * NN;          // B*N

    // 2048 rows, 4 waves per 256-thread block -> 512 blocks
    stats_kernel<<<(BB * NN) / 4, 256, 0, stream>>>(i_em, W_a, gamma, beta, sq, sk);
    // 1D grid, XCD-swizzled inside the kernel
    attn_kernel<<<(BB * NN / TI) * JC, 256, 0, stream>>>(i_em, sq, sk, b_a, alphas, value);
}